// Round 4
// baseline (770.440 us; speedup 1.0000x reference)
//
#include <hip/hip_runtime.h>
#include <math.h>

#define EMBED 64

// out[0] = h0 (layer-0 embedding), straight float4 copy
__global__ void copy_h0_kernel(const float* __restrict__ h0, float* __restrict__ out, int n4) {
    int i = blockIdx.x * blockDim.x + threadIdx.x;
    if (i < n4) ((float4*)out)[i] = ((const float4*)h0)[i];
}

// edge_row is sorted ascending -> build CSR row_ptr[N+1] by boundary scatter
__global__ void build_rowptr_kernel(const int* __restrict__ row, int* __restrict__ rp, int E, int N) {
    int i = blockIdx.x * blockDim.x + threadIdx.x;
    if (i >= E) return;
    if (i == 0) {
        int r0 = row[0];
        for (int r = 0; r <= r0; ++r) rp[r] = 0;
    } else {
        int a = row[i - 1], b = row[i];
        for (int r = a + 1; r <= b; ++r) rp[r] = i;
    }
    if (i == E - 1) {
        int rl = row[E - 1];
        for (int r = rl + 1; r <= N; ++r) rp[r] = E;
    }
}

// one LANE per edge: logits[e] = dot(h_att[row[e]], t_att[col[e]])
__global__ void __launch_bounds__(256) edge_logits_kernel(
        const float* __restrict__ ha, const float* __restrict__ ta,
        const int* __restrict__ row, const int* __restrict__ col,
        float* __restrict__ logits, int E) {
    int e = blockIdx.x * blockDim.x + threadIdx.x;
    if (e >= E) return;
    const float4* ha4 = (const float4*)(ha + (size_t)row[e] * EMBED);
    const float4* ta4 = (const float4*)(ta + (size_t)col[e] * EMBED);
    float4 acc = make_float4(0.f, 0.f, 0.f, 0.f);
    #pragma unroll
    for (int q = 0; q < 16; ++q) {
        float4 a = ha4[q];
        float4 t = ta4[q];
        acc.x = fmaf(a.x, t.x, acc.x);
        acc.y = fmaf(a.y, t.y, acc.y);
        acc.z = fmaf(a.z, t.z, acc.z);
        acc.w = fmaf(a.w, t.w, acc.w);
    }
    logits[e] = (acc.x + acc.y) + (acc.z + acc.w);
}

// one WAVE per node: softmax over CSR range, in-place logits -> weights.
__global__ void __launch_bounds__(256) node_softmax_kernel(
        const int* __restrict__ rp, float* __restrict__ lw, int N) {
    int n = (blockIdx.x * blockDim.x + threadIdx.x) >> 6;
    int lane = threadIdx.x & 63;
    if (n >= N) return;
    int s = rp[n], t = rp[n + 1];
    int deg = t - s;
    if (deg <= 0) return;

    if (deg <= 64) {
        float v = (lane < deg) ? lw[s + lane] : -INFINITY;
        float m = v;
        #pragma unroll
        for (int off = 32; off > 0; off >>= 1) m = fmaxf(m, __shfl_xor(m, off));
        float e = (lane < deg) ? expf(v - m) : 0.f;
        float sum = e;
        #pragma unroll
        for (int off = 32; off > 0; off >>= 1) sum += __shfl_xor(sum, off);
        float inv = 1.f / fmaxf(sum, 1e-12f);
        if (lane < deg) lw[s + lane] = e * inv;
    } else {
        float m = -INFINITY;
        for (int e = s + lane; e < t; e += 64) m = fmaxf(m, lw[e]);
        #pragma unroll
        for (int off = 32; off > 0; off >>= 1) m = fmaxf(m, __shfl_xor(m, off));
        float sum = 0.f;
        for (int e = s + lane; e < t; e += 64) sum += expf(lw[e] - m);
        #pragma unroll
        for (int off = 32; off > 0; off >>= 1) sum += __shfl_xor(sum, off);
        float inv = 1.f / fmaxf(sum, 1e-12f);
        for (int e = s + lane; e < t; e += 64) lw[e] = expf(lw[e] - m) * inv;
    }
}

// one wave per node (grid-stride). Gather layout: 16 lanes per edge, float4
// per lane -> one global_load_dwordx4 covers 4 edges (1 KB in flight per
// instruction), unroll x4 -> 16 edges / 4 KB in flight per batch.
// group g = lane>>4 picks the edge, sub = lane&15 picks features sub*4..+3.
__global__ void __launch_bounds__(256) prop_layer_kernel(
        const float* __restrict__ h_in,
        const float* __restrict__ W, const float* __restrict__ b,
        const int* __restrict__ col, const float* __restrict__ ew,
        const int* __restrict__ rp,
        float* __restrict__ out, int N, int totalWaves) {
    int wid = (blockIdx.x * blockDim.x + threadIdx.x) >> 6;
    int lane = threadIdx.x & 63;
    int g = lane >> 4;     // edge slot within a 4-edge batch
    int sub = lane & 15;   // feature quad

    // lane i holds W[i][0..63] in 64 VGPRs
    float4 Wr[16];
    const float4* W4 = (const float4*)W;
    #pragma unroll
    for (int q = 0; q < 16; ++q) Wr[q] = W4[lane * 16 + q];
    float bias = b[lane];

    for (int n = wid; n < N; n += totalWaves) {
        int s = rp[n], t = rp[n + 1];
        float self = h_in[(size_t)n * EMBED + lane];  // overlaps with gathers

        float4 acc = make_float4(0.f, 0.f, 0.f, 0.f);
        for (int eb = s; eb < t; eb += 16) {
            #pragma unroll
            for (int u = 0; u < 4; ++u) {
                int eg = eb + 4 * u + g;
                bool valid = eg < t;
                int cg = col[valid ? eg : (t - 1)];
                float wg = valid ? ew[eg] : 0.f;
                float4 v = *((const float4*)(h_in + (size_t)cg * EMBED) + sub);
                acc.x = fmaf(wg, v.x, acc.x);
                acc.y = fmaf(wg, v.y, acc.y);
                acc.z = fmaf(wg, v.z, acc.z);
                acc.w = fmaf(wg, v.w, acc.w);
            }
        }
        // reduce across the 4 edge groups (lanes sub, sub+16, sub+32, sub+48)
        #pragma unroll
        for (int off = 16; off < 64; off <<= 1) {
            acc.x += __shfl_xor(acc.x, off);
            acc.y += __shfl_xor(acc.y, off);
            acc.z += __shfl_xor(acc.z, off);
            acc.w += __shfl_xor(acc.w, off);
        }
        // redistribute so lane f holds feature f = sub*4 + comp
        int src = lane >> 2;
        float a0 = __shfl(acc.x, src);
        float a1 = __shfl(acc.y, src);
        float a2 = __shfl(acc.z, src);
        float a3 = __shfl(acc.w, src);
        int r = lane & 3;
        float msg = (r == 0) ? a0 : (r == 1) ? a1 : (r == 2) ? a2 : a3;
        float addv = self + msg;

        float x = bias;
        #pragma unroll
        for (int j = 0; j < 16; ++j) {
            float4 wv = Wr[j];
            x = fmaf(__shfl(addv, 4 * j + 0), wv.x, x);
            x = fmaf(__shfl(addv, 4 * j + 1), wv.y, x);
            x = fmaf(__shfl(addv, 4 * j + 2), wv.z, x);
            x = fmaf(__shfl(addv, 4 * j + 3), wv.w, x);
        }
        x = fmaxf(x, 0.f);

        float ss = x * x;
        #pragma unroll
        for (int off = 32; off > 0; off >>= 1) ss += __shfl_xor(ss, off);
        float nrm = sqrtf(ss);
        float scale = 1.f / fmaxf(nrm, 1e-12f);
        out[(size_t)n * EMBED + lane] = x * scale;
    }
}

extern "C" void kernel_launch(void* const* d_in, const int* in_sizes, int n_in,
                              void* d_out, int out_size, void* d_ws, size_t ws_size,
                              hipStream_t stream) {
    const float* h0   = (const float*)d_in[0];
    const float* ha   = (const float*)d_in[1];
    const float* ta   = (const float*)d_in[2];
    const float* w1   = (const float*)d_in[3];
    const float* b1   = (const float*)d_in[4];
    const float* w2   = (const float*)d_in[5];
    const float* b2   = (const float*)d_in[6];
    const int*   erow = (const int*)d_in[7];
    const int*   ecol = (const int*)d_in[8];

    const int N = in_sizes[0] / EMBED;
    const int E = in_sizes[7];
    float* out = (float*)d_out;

    // workspace layout: row_ptr[N+1] ints, then edge weights[E] floats
    int*   rp = (int*)d_ws;
    size_t rp_bytes = ((size_t)(N + 1) * sizeof(int) + 255) & ~(size_t)255;
    float* ew = (float*)((char*)d_ws + rp_bytes);

    // 1. out[0] = h0
    {
        int n4 = N * EMBED / 4;
        copy_h0_kernel<<<(n4 + 255) / 256, 256, 0, stream>>>(h0, out, n4);
    }
    // 2. CSR row_ptr
    build_rowptr_kernel<<<(E + 255) / 256, 256, 0, stream>>>(erow, rp, E, N);
    // 3. edge logits (one lane/edge)
    edge_logits_kernel<<<(E + 255) / 256, 256, 0, stream>>>(ha, ta, erow, ecol, ew, E);
    // 4. per-node softmax (one wave/node, in-place logits -> weights)
    {
        int waves_per_block = 256 / 64;
        int blocks = (N + waves_per_block - 1) / waves_per_block;
        node_softmax_kernel<<<blocks, 256, 0, stream>>>(rp, ew, N);
    }

    // 5. layer 1: h0 -> out[1];  layer 2: out[1] -> out[2]
    const int blocks = 2048;
    const int totalWaves = blocks * (256 / 64);
    float* out1 = out + (size_t)N * EMBED;
    float* out2 = out + 2 * (size_t)N * EMBED;
    prop_layer_kernel<<<blocks, 256, 0, stream>>>(h0,   w1, b1, ecol, ew, rp, out1, N, totalWaves);
    prop_layer_kernel<<<blocks, 256, 0, stream>>>(out1, w2, b2, ecol, ew, rp, out2, N, totalWaves);
}